// Round 1
// baseline (640.556 us; speedup 1.0000x reference)
//
#include <hip/hip_runtime.h>
#include <math.h>

#define NPIX 50176      // 16*56*56
#define CDIM 384
#define HEADS 6
#define NLOGIT 54       // HEADS*9
#define HH 56
#define WW 56

// ---------------------------------------------------------------------------
// Kernel 1: per-pixel attention logits + softmax over 3x3 window per head.
// One block (64 threads) per pixel. x row staged in LDS.
// attn layout: [NPIX][head*9 + w]
// ---------------------------------------------------------------------------
__global__ __launch_bounds__(64) void attn_softmax_kernel(
    const float* __restrict__ x, const float* __restrict__ W_attn,
    const float* __restrict__ b_attn, float* __restrict__ attn) {
  const int p = blockIdx.x;
  const int t = threadIdx.x;
  __shared__ float xs[CDIM];
  __shared__ float logits[NLOGIT];

  for (int i = t; i < CDIM; i += 64) xs[i] = x[(size_t)p * CDIM + i];
  __syncthreads();

  if (t < NLOGIT) {
    float acc = b_attn[t];
    #pragma unroll 4
    for (int c = 0; c < CDIM; ++c) acc += xs[c] * W_attn[(size_t)c * NLOGIT + t];
    logits[t] = acc;
  }
  __syncthreads();

  if (t < HEADS) {
    float m = -1e30f;
    #pragma unroll
    for (int w = 0; w < 9; ++w) m = fmaxf(m, logits[t * 9 + w]);
    float e[9];
    float s = 0.f;
    #pragma unroll
    for (int w = 0; w < 9; ++w) { e[w] = expf(logits[t * 9 + w] - m); s += e[w]; }
    const float inv = 1.f / s;
    #pragma unroll
    for (int w = 0; w < 9; ++w) attn[(size_t)p * NLOGIT + t * 9 + w] = e[w] * inv;
  }
}

// ---------------------------------------------------------------------------
// Kernel 2/4: fp32 tiled GEMM with bias. Out[M,N] = X[M,K] @ Wm[K,N] + bias[N]
// BM=BN=64, BK=16, 256 threads, 4x4 micro-tile per thread.
// M%64==0, N%64==0, K%16==0 assumed (holds: 50176, 384, 384).
// ---------------------------------------------------------------------------
template <int BM, int BN, int BK>
__global__ __launch_bounds__(256) void gemm_bias_kernel(
    const float* __restrict__ X, const float* __restrict__ Wm,
    const float* __restrict__ bias, float* __restrict__ Out,
    int M, int N, int Kd) {
  __shared__ float As[BK][BM + 4];   // [k][m], +4 keeps float4 alignment
  __shared__ float Bs[BK][BN + 4];   // [k][n]

  const int tid = threadIdx.x;
  const int bm = blockIdx.x * BM;
  const int bn = blockIdx.y * BN;
  const int tr = tid >> 4;   // 0..15 (row group)
  const int tc = tid & 15;   // 0..15 (col group)

  float acc[4][4] = {};

  for (int k0 = 0; k0 < Kd; k0 += BK) {
    // A tile: 64 rows x 16 k. Thread loads float4 of k's from one row.
    {
      const int r  = tid >> 2;          // 0..63
      const int kc = (tid & 3) * 4;     // 0,4,8,12
      const float4 va =
          *(const float4*)&X[(size_t)(bm + r) * Kd + k0 + kc];
      As[kc + 0][r] = va.x;
      As[kc + 1][r] = va.y;
      As[kc + 2][r] = va.z;
      As[kc + 3][r] = va.w;
    }
    // B tile: 16 k-rows x 64 n. Thread loads float4 along n.
    {
      const int kr = tid >> 4;          // 0..15
      const int nc = (tid & 15) * 4;    // 0..60
      const float4 vb =
          *(const float4*)&Wm[(size_t)(k0 + kr) * N + bn + nc];
      *(float4*)&Bs[kr][nc] = vb;
    }
    __syncthreads();

    #pragma unroll
    for (int k = 0; k < BK; ++k) {
      const float4 a4 = *(const float4*)&As[k][tr * 4];
      const float4 b4 = *(const float4*)&Bs[k][tc * 4];
      const float av[4] = {a4.x, a4.y, a4.z, a4.w};
      const float bv[4] = {b4.x, b4.y, b4.z, b4.w};
      #pragma unroll
      for (int i = 0; i < 4; ++i)
        #pragma unroll
        for (int j = 0; j < 4; ++j) acc[i][j] += av[i] * bv[j];
    }
    __syncthreads();
  }

  #pragma unroll
  for (int i = 0; i < 4; ++i) {
    const int m = bm + tr * 4 + i;
    const int n0 = bn + tc * 4;
    float4 o;
    o.x = acc[i][0] + bias[n0 + 0];
    o.y = acc[i][1] + bias[n0 + 1];
    o.z = acc[i][2] + bias[n0 + 2];
    o.w = acc[i][3] + bias[n0 + 3];
    *(float4*)&Out[(size_t)m * N + n0] = o;
  }
}

// ---------------------------------------------------------------------------
// Kernel 3: window aggregation.
// y[p, c] = sum_{ki,kj} attn[p, head(c), ki*3+kj] * v[nbr(p,ki,kj), c]
// One thread per (pixel, 4 channels).
// ---------------------------------------------------------------------------
__global__ __launch_bounds__(256) void aggregate_kernel(
    const float* __restrict__ v, const float* __restrict__ attn,
    float* __restrict__ y) {
  const int idx = blockIdx.x * blockDim.x + threadIdx.x;
  if (idx >= NPIX * (CDIM / 4)) return;
  const int p  = idx / (CDIM / 4);
  const int c  = (idx % (CDIM / 4)) * 4;
  const int b  = p / (HH * WW);
  const int ij = p % (HH * WW);
  const int i  = ij / WW;
  const int j  = ij % WW;
  const int head = c >> 6;   // c/64

  const float* ap = attn + (size_t)p * NLOGIT + head * 9;
  float aw[9];
  #pragma unroll
  for (int w = 0; w < 9; ++w) aw[w] = ap[w];

  float4 acc = {0.f, 0.f, 0.f, 0.f};
  #pragma unroll
  for (int ki = 0; ki < 3; ++ki) {
    const int ii = i + ki - 1;
    if (ii < 0 || ii >= HH) continue;
    #pragma unroll
    for (int kj = 0; kj < 3; ++kj) {
      const int jj = j + kj - 1;
      if (jj < 0 || jj >= WW) continue;
      const float w = aw[ki * 3 + kj];
      const float4 vv =
          *(const float4*)&v[((size_t)(b * HH + ii) * WW + jj) * CDIM + c];
      acc.x += w * vv.x;
      acc.y += w * vv.y;
      acc.z += w * vv.z;
      acc.w += w * vv.w;
    }
  }
  *(float4*)&y[(size_t)p * CDIM + c] = acc;
}

// ---------------------------------------------------------------------------
extern "C" void kernel_launch(void* const* d_in, const int* in_sizes, int n_in,
                              void* d_out, int out_size, void* d_ws,
                              size_t ws_size, hipStream_t stream) {
  const float* x      = (const float*)d_in[0];
  const float* W_attn = (const float*)d_in[1];
  const float* b_attn = (const float*)d_in[2];
  const float* W_v    = (const float*)d_in[3];
  const float* b_v    = (const float*)d_in[4];
  const float* W_proj = (const float*)d_in[5];
  const float* b_proj = (const float*)d_in[6];
  float* out = (float*)d_out;

  float* v    = (float*)d_ws;                       // NPIX*384 f32 (77 MB)
  float* y    = v + (size_t)NPIX * CDIM;            // NPIX*384 f32 (77 MB)
  float* attn = y + (size_t)NPIX * CDIM;            // NPIX*54  f32 (10.8 MB)

  // 1. attention weights
  attn_softmax_kernel<<<NPIX, 64, 0, stream>>>(x, W_attn, b_attn, attn);

  // 2. v = x @ W_v + b_v
  dim3 gemm_grid(NPIX / 64, CDIM / 64);
  gemm_bias_kernel<64, 64, 16>
      <<<gemm_grid, 256, 0, stream>>>(x, W_v, b_v, v, NPIX, CDIM, CDIM);

  // 3. window aggregation
  const int agg_threads = NPIX * (CDIM / 4);
  aggregate_kernel<<<(agg_threads + 255) / 256, 256, 0, stream>>>(v, attn, y);

  // 4. out = y @ W_proj + b_proj
  gemm_bias_kernel<64, 64, 16>
      <<<gemm_grid, 256, 0, stream>>>(y, W_proj, b_proj, out, NPIX, CDIM, CDIM);
}

// Round 2
// 174.426 us; speedup vs baseline: 3.6724x; 3.6724x over previous
//
#include <hip/hip_runtime.h>
#include <math.h>

#define NPIX 50176      // 16*56*56
#define CDIM 384
#define HEADS 6
#define NLOGIT 54       // HEADS*9
#define HH 56
#define WW 56

typedef __attribute__((ext_vector_type(8))) __bf16 bf16x8;
typedef __attribute__((ext_vector_type(4))) float f32x4;

__device__ __forceinline__ void glds16(const void* g, void* l) {
  __builtin_amdgcn_global_load_lds(
      (const __attribute__((address_space(1))) unsigned int*)g,
      (__attribute__((address_space(3))) unsigned int*)l, 16, 0, 0);
}

// ---------------------------------------------------------------------------
// Pad W_attn [384][54] -> Wpad [384][64] (zeros in cols 54..63), pad bias.
// ---------------------------------------------------------------------------
__global__ __launch_bounds__(256) void pad_attn_kernel(
    const float* __restrict__ W, const float* __restrict__ b,
    float* __restrict__ Wpad, float* __restrict__ bpad) {
  const int idx = blockIdx.x * 256 + threadIdx.x;
  if (idx < 384 * 64) {
    const int k = idx >> 6, n = idx & 63;
    Wpad[idx] = (n < NLOGIT) ? W[k * NLOGIT + n] : 0.f;
  }
  if (idx < 64) bpad[idx] = (idx < NLOGIT) ? b[idx] : 0.f;
}

// ---------------------------------------------------------------------------
// Cast + transpose weight: W fp32 [K][N] (384x384) -> Wt bf16 [N][K].
// ---------------------------------------------------------------------------
__global__ __launch_bounds__(256) void cast_wt_kernel(
    const float* __restrict__ W, __bf16* __restrict__ Wt) {
  const int idx = blockIdx.x * 256 + threadIdx.x;  // 384*384 = 147456
  const int n = idx / CDIM, k = idx % CDIM;
  Wt[n * CDIM + k] = (__bf16)W[k * CDIM + n];
}

// ---------------------------------------------------------------------------
// Cast x fp32 -> bf16, 8 elements / thread.
// ---------------------------------------------------------------------------
__global__ __launch_bounds__(256) void cast_x_kernel(
    const float* __restrict__ x, __bf16* __restrict__ xb) {
  const int i = blockIdx.x * 256 + threadIdx.x;  // NPIX*CDIM/8 = 2408448
  const float4 f0 = ((const float4*)x)[i * 2];
  const float4 f1 = ((const float4*)x)[i * 2 + 1];
  bf16x8 o;
  o[0] = (__bf16)f0.x; o[1] = (__bf16)f0.y; o[2] = (__bf16)f0.z; o[3] = (__bf16)f0.w;
  o[4] = (__bf16)f1.x; o[5] = (__bf16)f1.y; o[6] = (__bf16)f1.z; o[7] = (__bf16)f1.w;
  ((bf16x8*)xb)[i] = o;
}

// ---------------------------------------------------------------------------
// Logits GEMM (fp32, 64x64 tile, K=384) + fused per-head 9-window softmax.
// attn out layout: [NPIX][head*9+w]
// ---------------------------------------------------------------------------
__global__ __launch_bounds__(256) void logit_softmax_kernel(
    const float* __restrict__ X, const float* __restrict__ Wpad,
    const float* __restrict__ bpad, float* __restrict__ attn) {
  __shared__ float smem[64 * 68];
  float (*As)[68] = (float(*)[68])smem;               // [16][68] (k, m)
  float (*Bs)[68] = (float(*)[68])(smem + 16 * 68);   // [16][68] (k, n)

  const int tid = threadIdx.x;
  const int bm = blockIdx.x * 64;
  const int tr = tid >> 4;   // 0..15
  const int tc = tid & 15;   // 0..15

  float acc[4][4] = {};

  for (int k0 = 0; k0 < CDIM; k0 += 16) {
    {
      const int r  = tid >> 2;
      const int kc = (tid & 3) * 4;
      const float4 va = *(const float4*)&X[(size_t)(bm + r) * CDIM + k0 + kc];
      As[kc + 0][r] = va.x;
      As[kc + 1][r] = va.y;
      As[kc + 2][r] = va.z;
      As[kc + 3][r] = va.w;
    }
    {
      const int kr = tid >> 4;
      const int nc = (tid & 15) * 4;
      *(float4*)&Bs[kr][nc] = *(const float4*)&Wpad[(k0 + kr) * 64 + nc];
    }
    __syncthreads();

    #pragma unroll
    for (int k = 0; k < 16; ++k) {
      const float4 a4 = *(const float4*)&As[k][tr * 4];
      const float4 b4 = *(const float4*)&Bs[k][tc * 4];
      const float av[4] = {a4.x, a4.y, a4.z, a4.w};
      const float bv[4] = {b4.x, b4.y, b4.z, b4.w};
      #pragma unroll
      for (int i = 0; i < 4; ++i)
        #pragma unroll
        for (int j = 0; j < 4; ++j) acc[i][j] += av[i] * bv[j];
    }
    __syncthreads();
  }

  // stage logits (+bias) into LDS: Ls[64 pixels][68]
  float (*Ls)[68] = (float(*)[68])smem;
  const float4 bb = *(const float4*)&bpad[tc * 4];
  const float bv[4] = {bb.x, bb.y, bb.z, bb.w};
  #pragma unroll
  for (int i = 0; i < 4; ++i)
    #pragma unroll
    for (int j = 0; j < 4; ++j) Ls[tr * 4 + i][tc * 4 + j] = acc[i][j] + bv[j];
  __syncthreads();

  // 64 pixels * 6 heads = 384 softmax tasks over 256 threads
  for (int task = tid; task < 64 * HEADS; task += 256) {
    const int pl = task / HEADS;
    const int h  = task % HEADS;
    const float* row = &Ls[pl][h * 9];
    float m = row[0];
    #pragma unroll
    for (int w = 1; w < 9; ++w) m = fmaxf(m, row[w]);
    float e[9], s = 0.f;
    #pragma unroll
    for (int w = 0; w < 9; ++w) { e[w] = expf(row[w] - m); s += e[w]; }
    const float inv = 1.f / s;
    float* op = &attn[(size_t)(bm + pl) * NLOGIT + h * 9];
    #pragma unroll
    for (int w = 0; w < 9; ++w) op[w] = e[w] * inv;
  }
}

// ---------------------------------------------------------------------------
// bf16 MFMA GEMM: Out[M][N] = A[M][K] @ Bt[N][K]^T + bias.
// 128x128 tile, BK=32, 256 threads (4 waves, 2x2 of 64x64 wave-tiles).
// ---------------------------------------------------------------------------
template <bool OUT_BF16>
__global__ __launch_bounds__(256) void gemm_bf16_kernel(
    const __bf16* __restrict__ A, const __bf16* __restrict__ Bt,
    const float* __restrict__ bias, void* __restrict__ Out,
    int M, int N, int Kd) {
  __shared__ __bf16 As[128][32];
  __shared__ __bf16 Bs[128][32];

  const int tid  = threadIdx.x;
  const int wave = tid >> 6;
  const int lane = tid & 63;
  const int bm = blockIdx.x * 128;
  const int bn = blockIdx.y * 128;

  const int lrow   = lane >> 2;        // 0..15 (row within 16-row chunk)
  const int lkoff  = (lane & 3) * 8;   // k element offset 0,8,16,24
  const int frow   = lane & 15;        // fragment row/col
  const int fk     = (lane >> 4) * 8;  // fragment k offset
  const int wr = (wave >> 1) * 64;
  const int wc = (wave & 1) * 64;

  f32x4 acc[4][4] = {};

  for (int k0 = 0; k0 < Kd; k0 += 32) {
    const __bf16* ga = A  + (size_t)(bm + wave * 32 + lrow) * Kd + k0 + lkoff;
    const __bf16* gb = Bt + (size_t)(bn + wave * 32 + lrow) * Kd + k0 + lkoff;
    glds16(ga,                    &As[wave * 32][0]);
    glds16(ga + 16 * (size_t)Kd,  &As[wave * 32 + 16][0]);
    glds16(gb,                    &Bs[wave * 32][0]);
    glds16(gb + 16 * (size_t)Kd,  &Bs[wave * 32 + 16][0]);
    __syncthreads();

    bf16x8 a[4], b[4];
    #pragma unroll
    for (int mi = 0; mi < 4; ++mi)
      a[mi] = *(const bf16x8*)&As[wr + mi * 16 + frow][fk];
    #pragma unroll
    for (int ni = 0; ni < 4; ++ni)
      b[ni] = *(const bf16x8*)&Bs[wc + ni * 16 + frow][fk];
    #pragma unroll
    for (int mi = 0; mi < 4; ++mi)
      #pragma unroll
      for (int ni = 0; ni < 4; ++ni)
        acc[mi][ni] = __builtin_amdgcn_mfma_f32_16x16x32_bf16(
            a[mi], b[ni], acc[mi][ni], 0, 0, 0);
    __syncthreads();
  }

  const int orow = (lane >> 4) * 4;
  const int ocol = lane & 15;
  #pragma unroll
  for (int mi = 0; mi < 4; ++mi) {
    #pragma unroll
    for (int ni = 0; ni < 4; ++ni) {
      const int n = bn + wc + ni * 16 + ocol;
      const float bvl = bias[n];
      #pragma unroll
      for (int r = 0; r < 4; ++r) {
        const int m = bm + wr + mi * 16 + orow + r;
        const float val = acc[mi][ni][r] + bvl;
        if (OUT_BF16)
          ((__bf16*)Out)[(size_t)m * N + n] = (__bf16)val;
        else
          ((float*)Out)[(size_t)m * N + n] = val;
      }
    }
  }
}

// ---------------------------------------------------------------------------
// Window aggregation on bf16 v: y[p,c] = sum_w attn[p,head(c),w]*v[nbr(p,w),c]
// 8 channels / thread.
// ---------------------------------------------------------------------------
__global__ __launch_bounds__(256) void aggregate_kernel(
    const __bf16* __restrict__ v, const float* __restrict__ attn,
    __bf16* __restrict__ y) {
  const int idx = blockIdx.x * 256 + threadIdx.x;  // NPIX*48
  const int p  = idx / 48;
  const int cg = idx % 48;
  const int c  = cg * 8;
  const int b  = p / (HH * WW);
  const int ij = p % (HH * WW);
  const int i  = ij / WW;
  const int j  = ij % WW;
  const int head = c >> 6;

  const float* ap = attn + (size_t)p * NLOGIT + head * 9;
  float aw[9];
  #pragma unroll
  for (int w = 0; w < 9; ++w) aw[w] = ap[w];

  float acc[8] = {};
  #pragma unroll
  for (int ki = 0; ki < 3; ++ki) {
    const int ii = i + ki - 1;
    if (ii < 0 || ii >= HH) continue;
    #pragma unroll
    for (int kj = 0; kj < 3; ++kj) {
      const int jj = j + kj - 1;
      if (jj < 0 || jj >= WW) continue;
      const float w = aw[ki * 3 + kj];
      const bf16x8 vv =
          *(const bf16x8*)&v[((size_t)(b * HH + ii) * WW + jj) * CDIM + c];
      #pragma unroll
      for (int q = 0; q < 8; ++q) acc[q] += w * (float)vv[q];
    }
  }
  bf16x8 o;
  #pragma unroll
  for (int q = 0; q < 8; ++q) o[q] = (__bf16)acc[q];
  *(bf16x8*)&y[(size_t)p * CDIM + c] = o;
}

// ---------------------------------------------------------------------------
extern "C" void kernel_launch(void* const* d_in, const int* in_sizes, int n_in,
                              void* d_out, int out_size, void* d_ws,
                              size_t ws_size, hipStream_t stream) {
  const float* x      = (const float*)d_in[0];
  const float* W_attn = (const float*)d_in[1];
  const float* b_attn = (const float*)d_in[2];
  const float* W_v    = (const float*)d_in[3];
  const float* b_v    = (const float*)d_in[4];
  const float* W_proj = (const float*)d_in[5];
  const float* b_proj = (const float*)d_in[6];
  float* out = (float*)d_out;

  char* w = (char*)d_ws;
  __bf16* xb   = (__bf16*)w;              w += (size_t)NPIX * CDIM * 2;  // 38.5MB
  __bf16* v    = (__bf16*)w;              w += (size_t)NPIX * CDIM * 2;  // 38.5MB
  __bf16* y    = (__bf16*)w;              w += (size_t)NPIX * CDIM * 2;  // 38.5MB
  float*  attn = (float*)w;               w += (size_t)NPIX * NLOGIT * 4; // 10.8MB
  float*  Wpad = (float*)w;               w += 384 * 64 * 4;
  float*  bpad = (float*)w;               w += 256;
  __bf16* Wtv  = (__bf16*)w;              w += CDIM * CDIM * 2;
  __bf16* Wtp  = (__bf16*)w;              w += CDIM * CDIM * 2;

  // prep: pad attn weights, cast/transpose big weights, cast x
  pad_attn_kernel<<<(384 * 64 + 255) / 256, 256, 0, stream>>>(W_attn, b_attn, Wpad, bpad);
  cast_wt_kernel<<<(CDIM * CDIM) / 256, 256, 0, stream>>>(W_v, Wtv);
  cast_wt_kernel<<<(CDIM * CDIM) / 256, 256, 0, stream>>>(W_proj, Wtp);
  cast_x_kernel<<<(NPIX * CDIM / 8) / 256, 256, 0, stream>>>(x, xb);

  // 1. attention logits + softmax
  logit_softmax_kernel<<<NPIX / 64, 256, 0, stream>>>(x, Wpad, bpad, attn);

  // 2. v = bf16(x @ W_v + b_v)
  dim3 ggrid(NPIX / 128, CDIM / 128);
  gemm_bf16_kernel<true>
      <<<ggrid, 256, 0, stream>>>(xb, Wtv, b_v, v, NPIX, CDIM, CDIM);

  // 3. window aggregation -> y (bf16)
  aggregate_kernel<<<(NPIX * 48) / 256, 256, 0, stream>>>(v, attn, y);

  // 4. out = y @ W_proj + b_proj (fp32 out)
  gemm_bf16_kernel<false>
      <<<ggrid, 256, 0, stream>>>(y, Wtp, b_proj, out, NPIX, CDIM, CDIM);
}

// Round 3
// 143.832 us; speedup vs baseline: 4.4535x; 1.2127x over previous
//
#include <hip/hip_runtime.h>
#include <math.h>

#define NPIX 50176      // 16*56*56
#define CDIM 384
#define HEADS 6
#define NLOGIT 54       // HEADS*9
#define HH 56
#define WW 56

typedef __attribute__((ext_vector_type(8))) __bf16 bf16x8;
typedef __attribute__((ext_vector_type(4))) float f32x4;

__device__ __forceinline__ void glds16(const void* g, void* l) {
  __builtin_amdgcn_global_load_lds(
      (const __attribute__((address_space(1))) unsigned int*)g,
      (__attribute__((address_space(3))) unsigned int*)l, 16, 0, 0);
}

// ---------------------------------------------------------------------------
// W_attn [384][54] fp32 -> Wt bf16 [64][384] (transposed, zero-padded rows
// 54..63); b_attn -> bpad[64] fp32.
// ---------------------------------------------------------------------------
__global__ __launch_bounds__(256) void pad_attn_kernel(
    const float* __restrict__ W, const float* __restrict__ b,
    __bf16* __restrict__ Wt, float* __restrict__ bpad) {
  const int idx = blockIdx.x * 256 + threadIdx.x;  // 64*384 = 24576
  if (idx < 64 * CDIM) {
    const int n = idx / CDIM, k = idx % CDIM;
    Wt[idx] = (__bf16)((n < NLOGIT) ? W[k * NLOGIT + n] : 0.f);
  }
  if (idx < 64) bpad[idx] = (idx < NLOGIT) ? b[idx] : 0.f;
}

// ---------------------------------------------------------------------------
// Cast + transpose weight: W fp32 [K][N] (384x384) -> Wt bf16 [N][K].
// ---------------------------------------------------------------------------
__global__ __launch_bounds__(256) void cast_wt_kernel(
    const float* __restrict__ W, __bf16* __restrict__ Wt) {
  const int idx = blockIdx.x * 256 + threadIdx.x;  // 384*384 = 147456
  const int n = idx / CDIM, k = idx % CDIM;
  Wt[n * CDIM + k] = (__bf16)W[k * CDIM + n];
}

// ---------------------------------------------------------------------------
// Logits via bf16 MFMA (BM=128, BN=64, BK=32) + fused softmax epilogue.
// Also emits the bf16 cast of x (xb) as a by-product of A-staging.
// attn out layout: [NPIX][head*9+w]
// ---------------------------------------------------------------------------
__global__ __launch_bounds__(256) void logit_softmax_kernel(
    const float* __restrict__ X, const __bf16* __restrict__ Wt,
    const float* __restrict__ bpad, float* __restrict__ attn,
    __bf16* __restrict__ xb) {
  __shared__ float smemf[128 * 68];                    // 34816 B
  __bf16 (*As)[40] = (__bf16(*)[40])smemf;             // 10240 B
  __bf16 (*Bs)[40] = (__bf16(*)[40])((char*)smemf + 10240);  // 5120 B
  float (*Ls)[68] = (float(*)[68])smemf;

  const int tid  = threadIdx.x;
  const int wave = tid >> 6;
  const int lane = tid & 63;
  const int bm   = blockIdx.x * 128;
  const int frow = lane & 15;
  const int fk   = (lane >> 4) * 8;

  const int ar  = tid >> 1;          // 0..127  (A-stage row)
  const int akc = (tid & 1) * 16;    // 0 or 16 (A-stage k offset)
  const int br  = tid >> 2;          // 0..63   (B-stage row)
  const int bkc = (tid & 3) * 8;

  f32x4 acc[2][4] = {};

  for (int k0 = 0; k0 < CDIM; k0 += 32) {
    // A: 16 fp32 -> 16 bf16 -> LDS + xb global
    const float* gx = X + (size_t)(bm + ar) * CDIM + k0 + akc;
    float fv[16];
    *(float4*)(fv + 0)  = *(const float4*)(gx + 0);
    *(float4*)(fv + 4)  = *(const float4*)(gx + 4);
    *(float4*)(fv + 8)  = *(const float4*)(gx + 8);
    *(float4*)(fv + 12) = *(const float4*)(gx + 12);
    bf16x8 h0, h1;
    #pragma unroll
    for (int q = 0; q < 8; ++q) {
      h0[q] = (__bf16)fv[q];
      h1[q] = (__bf16)fv[q + 8];
    }
    *(bf16x8*)&As[ar][akc]     = h0;
    *(bf16x8*)&As[ar][akc + 8] = h1;
    __bf16* gxb = xb + (size_t)(bm + ar) * CDIM + k0 + akc;
    *(bf16x8*)(gxb)     = h0;
    *(bf16x8*)(gxb + 8) = h1;
    // B: bf16 weight tile
    *(bf16x8*)&Bs[br][bkc] = *(const bf16x8*)&Wt[br * CDIM + k0 + bkc];
    __syncthreads();

    bf16x8 a[2], b[4];
    #pragma unroll
    for (int mi = 0; mi < 2; ++mi)
      a[mi] = *(const bf16x8*)&As[wave * 32 + mi * 16 + frow][fk];
    #pragma unroll
    for (int ni = 0; ni < 4; ++ni)
      b[ni] = *(const bf16x8*)&Bs[ni * 16 + frow][fk];
    #pragma unroll
    for (int mi = 0; mi < 2; ++mi)
      #pragma unroll
      for (int ni = 0; ni < 4; ++ni)
        acc[mi][ni] = __builtin_amdgcn_mfma_f32_16x16x32_bf16(
            a[mi], b[ni], acc[mi][ni], 0, 0, 0);
    __syncthreads();
  }

  // stage logits (+bias) into LDS
  float bvl[4];
  #pragma unroll
  for (int ni = 0; ni < 4; ++ni) bvl[ni] = bpad[ni * 16 + frow];
  const int orow = (lane >> 4) * 4;
  #pragma unroll
  for (int mi = 0; mi < 2; ++mi)
    #pragma unroll
    for (int ni = 0; ni < 4; ++ni)
      #pragma unroll
      for (int r = 0; r < 4; ++r)
        Ls[wave * 32 + mi * 16 + orow + r][ni * 16 + frow] =
            acc[mi][ni][r] + bvl[ni];
  __syncthreads();

  // 128 pixels * 6 heads = 768 softmax tasks over 256 threads (3 each)
  #pragma unroll
  for (int it = 0; it < 3; ++it) {
    const int task = it * 256 + tid;
    const int pl = task / HEADS;
    const int h  = task % HEADS;
    const float* row = &Ls[pl][h * 9];
    float m = row[0];
    #pragma unroll
    for (int w = 1; w < 9; ++w) m = fmaxf(m, row[w]);
    float e[9], s = 0.f;
    #pragma unroll
    for (int w = 0; w < 9; ++w) { e[w] = __expf(row[w] - m); s += e[w]; }
    const float inv = 1.f / s;
    float* op = &attn[(size_t)(bm + pl) * NLOGIT + h * 9];
    #pragma unroll
    for (int w = 0; w < 9; ++w) op[w] = e[w] * inv;
  }
}

// ---------------------------------------------------------------------------
// bf16 MFMA GEMM: Out[M][N] = A[M][K] @ Bt[N][K]^T + bias.
// 128x128 tile, BK=32, 256 threads (4 waves, 2x2 of 64x64 wave-tiles).
// ---------------------------------------------------------------------------
template <bool OUT_BF16>
__global__ __launch_bounds__(256) void gemm_bf16_kernel(
    const __bf16* __restrict__ A, const __bf16* __restrict__ Bt,
    const float* __restrict__ bias, void* __restrict__ Out,
    int M, int N, int Kd) {
  __shared__ __bf16 As[128][32];
  __shared__ __bf16 Bs[128][32];

  const int tid  = threadIdx.x;
  const int wave = tid >> 6;
  const int lane = tid & 63;
  const int bm = blockIdx.x * 128;
  const int bn = blockIdx.y * 128;

  const int lrow   = lane >> 2;        // 0..15
  const int lkoff  = (lane & 3) * 8;   // 0,8,16,24
  const int frow   = lane & 15;
  const int fk     = (lane >> 4) * 8;
  const int wr = (wave >> 1) * 64;
  const int wc = (wave & 1) * 64;

  f32x4 acc[4][4] = {};

  for (int k0 = 0; k0 < Kd; k0 += 32) {
    const __bf16* ga = A  + (size_t)(bm + wave * 32 + lrow) * Kd + k0 + lkoff;
    const __bf16* gb = Bt + (size_t)(bn + wave * 32 + lrow) * Kd + k0 + lkoff;
    glds16(ga,                    &As[wave * 32][0]);
    glds16(ga + 16 * (size_t)Kd,  &As[wave * 32 + 16][0]);
    glds16(gb,                    &Bs[wave * 32][0]);
    glds16(gb + 16 * (size_t)Kd,  &Bs[wave * 32 + 16][0]);
    __syncthreads();

    bf16x8 a[4], b[4];
    #pragma unroll
    for (int mi = 0; mi < 4; ++mi)
      a[mi] = *(const bf16x8*)&As[wr + mi * 16 + frow][fk];
    #pragma unroll
    for (int ni = 0; ni < 4; ++ni)
      b[ni] = *(const bf16x8*)&Bs[wc + ni * 16 + frow][fk];
    #pragma unroll
    for (int mi = 0; mi < 4; ++mi)
      #pragma unroll
      for (int ni = 0; ni < 4; ++ni)
        acc[mi][ni] = __builtin_amdgcn_mfma_f32_16x16x32_bf16(
            a[mi], b[ni], acc[mi][ni], 0, 0, 0);
    __syncthreads();
  }

  const int orow = (lane >> 4) * 4;
  const int ocol = lane & 15;
  #pragma unroll
  for (int mi = 0; mi < 4; ++mi) {
    #pragma unroll
    for (int ni = 0; ni < 4; ++ni) {
      const int n = bn + wc + ni * 16 + ocol;
      const float bvl = bias[n];
      #pragma unroll
      for (int r = 0; r < 4; ++r) {
        const int m = bm + wr + mi * 16 + orow + r;
        const float val = acc[mi][ni][r] + bvl;
        if (OUT_BF16)
          ((__bf16*)Out)[(size_t)m * N + n] = (__bf16)val;
        else
          ((float*)Out)[(size_t)m * N + n] = val;
      }
    }
  }
}

// ---------------------------------------------------------------------------
// Window aggregation on bf16 v: y[p,c] = sum_w attn[p,head(c),w]*v[nbr(p,w),c]
// ---------------------------------------------------------------------------
__global__ __launch_bounds__(256) void aggregate_kernel(
    const __bf16* __restrict__ v, const float* __restrict__ attn,
    __bf16* __restrict__ y) {
  const int idx = blockIdx.x * 256 + threadIdx.x;  // NPIX*48
  const int p  = idx / 48;
  const int cg = idx % 48;
  const int c  = cg * 8;
  const int b  = p / (HH * WW);
  const int ij = p % (HH * WW);
  const int i  = ij / WW;
  const int j  = ij % WW;
  const int head = c >> 6;

  const float* ap = attn + (size_t)p * NLOGIT + head * 9;
  float aw[9];
  #pragma unroll
  for (int w = 0; w < 9; ++w) aw[w] = ap[w];

  float acc[8] = {};
  #pragma unroll
  for (int ki = 0; ki < 3; ++ki) {
    const int ii = i + ki - 1;
    if (ii < 0 || ii >= HH) continue;
    #pragma unroll
    for (int kj = 0; kj < 3; ++kj) {
      const int jj = j + kj - 1;
      if (jj < 0 || jj >= WW) continue;
      const float w = aw[ki * 3 + kj];
      const bf16x8 vv =
          *(const bf16x8*)&v[((size_t)(b * HH + ii) * WW + jj) * CDIM + c];
      #pragma unroll
      for (int q = 0; q < 8; ++q) acc[q] += w * (float)vv[q];
    }
  }
  bf16x8 o;
  #pragma unroll
  for (int q = 0; q < 8; ++q) o[q] = (__bf16)acc[q];
  *(bf16x8*)&y[(size_t)p * CDIM + c] = o;
}

// ---------------------------------------------------------------------------
extern "C" void kernel_launch(void* const* d_in, const int* in_sizes, int n_in,
                              void* d_out, int out_size, void* d_ws,
                              size_t ws_size, hipStream_t stream) {
  const float* x      = (const float*)d_in[0];
  const float* W_attn = (const float*)d_in[1];
  const float* b_attn = (const float*)d_in[2];
  const float* W_v    = (const float*)d_in[3];
  const float* b_v    = (const float*)d_in[4];
  const float* W_proj = (const float*)d_in[5];
  const float* b_proj = (const float*)d_in[6];
  float* out = (float*)d_out;

  char* w = (char*)d_ws;
  __bf16* xb   = (__bf16*)w;  w += (size_t)NPIX * CDIM * 2;   // 38.5MB
  __bf16* v    = (__bf16*)w;  w += (size_t)NPIX * CDIM * 2;   // 38.5MB
  __bf16* y    = (__bf16*)w;  w += (size_t)NPIX * CDIM * 2;   // 38.5MB
  float*  attn = (float*)w;   w += (size_t)NPIX * NLOGIT * 4; // 10.8MB
  __bf16* Wta  = (__bf16*)w;  w += 64 * CDIM * 2;
  float*  bpad = (float*)w;   w += 64 * 4;
  __bf16* Wtv  = (__bf16*)w;  w += CDIM * CDIM * 2;
  __bf16* Wtp  = (__bf16*)w;  w += CDIM * CDIM * 2;

  // prep
  pad_attn_kernel<<<(64 * CDIM + 255) / 256, 256, 0, stream>>>(W_attn, b_attn, Wta, bpad);
  cast_wt_kernel<<<(CDIM * CDIM) / 256, 256, 0, stream>>>(W_v, Wtv);
  cast_wt_kernel<<<(CDIM * CDIM) / 256, 256, 0, stream>>>(W_proj, Wtp);

  // 1. logits + softmax (also produces xb)
  logit_softmax_kernel<<<NPIX / 128, 256, 0, stream>>>(x, Wta, bpad, attn, xb);

  // 2. v = bf16(x @ W_v + b_v)
  dim3 ggrid(NPIX / 128, CDIM / 128);
  gemm_bf16_kernel<true>
      <<<ggrid, 256, 0, stream>>>(xb, Wtv, b_v, v, NPIX, CDIM, CDIM);

  // 3. window aggregation -> y (bf16)
  aggregate_kernel<<<(NPIX * 48) / 256, 256, 0, stream>>>(v, attn, y);

  // 4. out = y @ W_proj + b_proj (fp32 out)
  gemm_bf16_kernel<false>
      <<<ggrid, 256, 0, stream>>>(y, Wtp, b_proj, out, NPIX, CDIM, CDIM);
}